// Round 1
// baseline (1914.556 us; speedup 1.0000x reference)
//
#include <hip/hip_runtime.h>

// SpikingReservoir: B=64, N_IN=8, T=3000, N_RES=512.
// One block per batch element; thread = reservoir neuron. Spikes carried as
// 8x u64 ballot masks in LDS (double-buffered, 1 barrier/step). Recurrent
// matvec done sparsely over active spike bits with coalesced reads of
// W_rec^T (pre-transposed into d_ws).

#define N_RES 512
#define N_IN 8
#define T_STEPS 3000
#define B_SIZE 64

__global__ __launch_bounds__(256) void transpose_wrec(const float* __restrict__ W,
                                                      float* __restrict__ WT) {
    int idx = blockIdx.x * blockDim.x + threadIdx.x;   // 0 .. 512*512-1
    int j = idx >> 9;        // WT row  (= W column)
    int r = idx & (N_RES - 1); // WT col (contiguous store)
    WT[idx] = W[r * N_RES + j];
}

template <bool USE_WT>
__global__ __launch_bounds__(512) void reservoir_kernel(
    const float* __restrict__ x,      // [B][N_IN][T]
    const float* __restrict__ W_in,   // [N_RES][N_IN]
    const float* __restrict__ W_rec,  // [N_RES][N_RES] (row r, col j)
    const float* __restrict__ WT,     // [j][r] transposed copy (in d_ws)
    float* __restrict__ out)          // [B][N_RES]
{
    __shared__ float xs[N_IN * T_STEPS];           // 96 KB: x for this batch
    __shared__ unsigned long long masks[2][8];     // double-buffered spike masks

    const int tid  = threadIdx.x;     // neuron index r
    const int b    = blockIdx.x;
    const int wave = tid >> 6;
    const int lane = tid & 63;

    // Stage x[b,:,:] into LDS (coalesced, one-time 96 KB)
    const float* xb = x + (size_t)b * (N_IN * T_STEPS);
    for (int i = tid; i < N_IN * T_STEPS; i += 512) xs[i] = xb[i];

    // This neuron's input weights (8 floats)
    float wi[N_IN];
#pragma unroll
    for (int k = 0; k < N_IN; ++k) wi[k] = W_in[tid * N_IN + k];

    if (tid < 16) ((unsigned long long*)masks)[tid] = 0ULL;

    float v = 0.0f, acc = 0.0f;
    __syncthreads();

    const float* wt_col = WT + tid;                 // coalesced: lane r reads WT[j*512 + r]
    const float* wr_row = W_rec + (size_t)tid * N_RES; // fallback: row r

    for (int t = 0; t < T_STEPS; ++t) {
        const int cur = t & 1;

        // input projection: sum_i W_in[r,i] * x[b,i,t]  (ascending i)
        float xp = 0.0f;
#pragma unroll
        for (int i = 0; i < N_IN; ++i) xp += wi[i] * xs[i * T_STEPS + t];

        // recurrent: sum over active presynaptic j (ascending j; block-uniform loop)
        float rec = 0.0f;
#pragma unroll
        for (int w = 0; w < 8; ++w) {
            unsigned long long m = masks[cur][w];
            while (m) {
                int j = (w << 6) + __builtin_ctzll(m);
                m &= (m - 1);
                if (USE_WT)
                    rec += wt_col[(size_t)j * N_RES];
                else
                    rec += wr_row[j];
            }
        }

        // LIF: charge, spike, hard reset (exact reference arithmetic order)
        float i_in = xp + rec;
        v = v + (i_in - v) * 0.5f;                  // /TAU, TAU=2 (exact)
        bool s = (v - 1.0f) >= 0.0f;
        unsigned long long bal = __ballot(s);
        if (s) { v = 0.0f; acc += 1.0f; }
        if (lane == 0) masks[cur ^ 1][wave] = bal;
        __syncthreads();
    }

    out[b * N_RES + tid] = acc / 3000.0f;
}

extern "C" void kernel_launch(void* const* d_in, const int* in_sizes, int n_in,
                              void* d_out, int out_size, void* d_ws, size_t ws_size,
                              hipStream_t stream) {
    const float* x     = (const float*)d_in[0];   // 64*8*3000
    const float* W_in  = (const float*)d_in[1];   // 512*8
    const float* W_rec = (const float*)d_in[2];   // 512*512
    float* out = (float*)d_out;                   // 64*512

    const size_t wt_bytes = (size_t)N_RES * N_RES * sizeof(float);
    if (ws_size >= wt_bytes) {
        float* WT = (float*)d_ws;
        transpose_wrec<<<(N_RES * N_RES) / 256, 256, 0, stream>>>(W_rec, WT);
        reservoir_kernel<true><<<B_SIZE, 512, 0, stream>>>(x, W_in, W_rec, WT, out);
    } else {
        // workspace too small for transposed copy: slower uncoalesced fallback
        reservoir_kernel<false><<<B_SIZE, 512, 0, stream>>>(x, W_in, W_rec, nullptr, out);
    }
}

// Round 2
// 688.629 us; speedup vs baseline: 2.7802x; 2.7802x over previous
//
#include <hip/hip_runtime.h>

// SpikingReservoir v2: B=64, N_IN=8, T=3000, N_RES=512.
// One WAVE per batch element (64 blocks x 64 threads); lane l owns neurons
// r = k*64 + l, k=0..7. Spike masks are __ballot results carried in
// (uniform) registers -- no LDS mask exchange, no __syncthreads in the
// 3000-step serial loop. x staged transposed in LDS as [t][8] so each step
// is two prefetched ds_read_b128 broadcasts. Input projection done as
// float2 ext-vectors to enable v_pk_fma_f32.

#define N_RES 512
#define N_IN 8
#define T_STEPS 3000
#define B_SIZE 64

typedef float v2f __attribute__((ext_vector_type(2)));
typedef float v4f __attribute__((ext_vector_type(4)));

__global__ __launch_bounds__(256) void transpose_wrec(const float* __restrict__ W,
                                                      float* __restrict__ WT) {
    int idx = blockIdx.x * blockDim.x + threadIdx.x;   // 0 .. 512*512-1
    int j = idx >> 9;          // WT row  (= W column)
    int r = idx & (N_RES - 1); // WT col (contiguous store)
    WT[idx] = W[r * N_RES + j];
}

template <bool USE_WT>
__global__ __launch_bounds__(64, 1) void reservoir_wave(
    const float* __restrict__ x,      // [B][N_IN][T]
    const float* __restrict__ W_in,   // [N_RES][N_IN]
    const float* __restrict__ W_rec,  // [N_RES][N_RES] (row r, col j)
    const float* __restrict__ WT,     // [j][r] transposed copy (in d_ws)
    float* __restrict__ out)          // [B][N_RES]
{
    // [t][8] layout, +1 padded step so the t+1 prefetch can over-read.
    __shared__ v4f xs4[2 * (T_STEPS + 1)];          // 96,032 B
    float* xsf = (float*)xs4;

    const int lane = threadIdx.x;                   // 0..63
    const int b = blockIdx.x;

    // Stage x[b,:,:] transposed: xsf[t*8+i] = x[b][i][t]. Reads coalesced.
    const float* xb = x + (size_t)b * (N_IN * T_STEPS);
#pragma unroll
    for (int i = 0; i < N_IN; ++i)
        for (int t = lane; t < T_STEPS; t += 64)
            xsf[t * 8 + i] = xb[i * T_STEPS + t];
    if (lane < 8) xsf[T_STEPS * 8 + lane] = 0.0f;   // pad step

    // Input weights, packed per neuron-pair: w2[p][i] = {W_in[r0,i], W_in[r1,i]}
    // with r0 = (2p)*64+lane, r1 = (2p+1)*64+lane.
    v2f w2[4][N_IN];
#pragma unroll
    for (int p = 0; p < 4; ++p) {
        const int r0 = (2 * p) * 64 + lane;
        const int r1 = r0 + 64;
#pragma unroll
        for (int i = 0; i < N_IN; ++i)
            w2[p][i] = (v2f){ W_in[r0 * N_IN + i], W_in[r1 * N_IN + i] };
    }

    v2f v[4], acc[4];
#pragma unroll
    for (int p = 0; p < 4; ++p) { v[p] = (v2f)0.0f; acc[p] = (v2f)0.0f; }

    unsigned long long mask[8];
#pragma unroll
    for (int k = 0; k < 8; ++k) mask[k] = 0ULL;

    __syncthreads();

    v4f xlo = xs4[0], xhi = xs4[1];

    for (int t = 0; t < T_STEPS; ++t) {
        // Prefetch next step's 8 x-values (bounded by the pad step).
        v4f nlo = xs4[2 * t + 2];
        v4f nhi = xs4[2 * t + 3];

        // Recurrent input from previous step's spikes (rare path).
        v2f rec[4];
#pragma unroll
        for (int p = 0; p < 4; ++p) rec[p] = (v2f)0.0f;

        const unsigned long long anym =
            mask[0] | mask[1] | mask[2] | mask[3] |
            mask[4] | mask[5] | mask[6] | mask[7];
        if (anym) {
#pragma unroll
            for (int k2 = 0; k2 < 8; ++k2) {
                unsigned long long m = mask[k2];
                while (m) {
                    const int j = (k2 << 6) + __builtin_ctzll(m);
                    m &= m - 1;
#pragma unroll
                    for (int p = 0; p < 4; ++p) {
                        const int r0 = (2 * p) * 64 + lane;
                        if (USE_WT) {
                            rec[p].x += WT[(size_t)j * N_RES + r0];
                            rec[p].y += WT[(size_t)j * N_RES + r0 + 64];
                        } else {
                            rec[p].x += W_rec[(size_t)r0 * N_RES + j];
                            rec[p].y += W_rec[(size_t)(r0 + 64) * N_RES + j];
                        }
                    }
                }
            }
        }

        // Input projection: xp[p] = rec[p] + sum_i w2[p][i] * x[i]
        const float xf[8] = { xlo.x, xlo.y, xlo.z, xlo.w,
                              xhi.x, xhi.y, xhi.z, xhi.w };
        v2f xp[4];
#pragma unroll
        for (int p = 0; p < 4; ++p) xp[p] = rec[p];
#pragma unroll
        for (int i = 0; i < N_IN; ++i) {
            const v2f xv = (v2f){ xf[i], xf[i] };
#pragma unroll
            for (int p = 0; p < 4; ++p) xp[p] += w2[p][i] * xv;
        }

        // LIF: charge, spike, hard reset (exact reference arithmetic order).
#pragma unroll
        for (int p = 0; p < 4; ++p) {
            v[p] = v[p] + (xp[p] - v[p]) * 0.5f;    // /TAU, TAU=2
            const bool s0 = (v[p].x - 1.0f) >= 0.0f;
            const bool s1 = (v[p].y - 1.0f) >= 0.0f;
            mask[2 * p]     = __ballot(s0);
            mask[2 * p + 1] = __ballot(s1);
            if (s0) { v[p].x = 0.0f; acc[p].x += 1.0f; }
            if (s1) { v[p].y = 0.0f; acc[p].y += 1.0f; }
        }

        xlo = nlo; xhi = nhi;
    }

#pragma unroll
    for (int p = 0; p < 4; ++p) {
        const int r0 = (2 * p) * 64 + lane;
        out[b * N_RES + r0]      = acc[p].x / (float)T_STEPS;
        out[b * N_RES + r0 + 64] = acc[p].y / (float)T_STEPS;
    }
}

extern "C" void kernel_launch(void* const* d_in, const int* in_sizes, int n_in,
                              void* d_out, int out_size, void* d_ws, size_t ws_size,
                              hipStream_t stream) {
    const float* x     = (const float*)d_in[0];   // 64*8*3000
    const float* W_in  = (const float*)d_in[1];   // 512*8
    const float* W_rec = (const float*)d_in[2];   // 512*512
    float* out = (float*)d_out;                   // 64*512

    const size_t wt_bytes = (size_t)N_RES * N_RES * sizeof(float);
    if (ws_size >= wt_bytes) {
        float* WT = (float*)d_ws;
        transpose_wrec<<<(N_RES * N_RES) / 256, 256, 0, stream>>>(W_rec, WT);
        reservoir_wave<true><<<B_SIZE, 64, 0, stream>>>(x, W_in, W_rec, WT, out);
    } else {
        reservoir_wave<false><<<B_SIZE, 64, 0, stream>>>(x, W_in, W_rec, nullptr, out);
    }
}

// Round 3
// 108.532 us; speedup vs baseline: 17.6405x; 6.3450x over previous
//
#include <hip/hip_runtime.h>

// SpikingReservoir v3: B=64, N_IN=8, T=3000, N_RES=512.
// Key insight: LIF decay is 0.5/step -> state memory is EXACTLY zero (f32
// underflow) after ~150 steps absent spikes, and for this input v sits ~10
// sigma below threshold so spikes never fire. So we run 10 independent time
// chunks (300 body + 150 warmup-from-zero) fully in parallel: 640 blocks x
// 512 threads, thread = neuron. A guard flag (v >= 0.75 anywhere) triggers a
// final exact serial fallback kernel (the validated v2 wave kernel), making
// the result correct for any input.
//
// ws layout: [int flag][pad to 256B][xT: B*T*8 f32][partial: B*CHUNKS*512 f32]

#define N_RES 512
#define N_IN 8
#define T_STEPS 3000
#define B_SIZE 64
#define CHUNKS 10
#define BODY 300
#define WARM 150

__global__ __launch_bounds__(64) void init_flag(int* flag) {
    if (threadIdx.x == 0) *flag = 0;
}

// xT[b][t][i] = x[b][i][t]; reads coalesced along t, each thread writes its
// own contiguous 32B (two float4).
__global__ __launch_bounds__(256) void transpose_x(const float* __restrict__ x,
                                                   float* __restrict__ xT) {
    int idx = blockIdx.x * blockDim.x + threadIdx.x;  // b*T + t, 750*256 total
    int b = idx / T_STEPS;
    int t = idx - b * T_STEPS;
    float r[N_IN];
#pragma unroll
    for (int i = 0; i < N_IN; ++i)
        r[i] = x[((size_t)b * N_IN + i) * T_STEPS + t];
    float4* o = (float4*)(xT + (size_t)idx * 8);
    o[0] = (float4){r[0], r[1], r[2], r[3]};
    o[1] = (float4){r[4], r[5], r[6], r[7]};
}

// One block per (batch, chunk); thread = neuron. No spikes assumed (guarded).
__global__ __launch_bounds__(512) void chunk_kernel(
    const float* __restrict__ xT,     // [B][T][8]
    const float* __restrict__ W_in,   // [N_RES][8]
    float* __restrict__ partial,      // [B][CHUNKS][N_RES] spike counts
    int* __restrict__ flag)
{
    const int blk = blockIdx.x;            // b*CHUNKS + c
    const int b = blk / CHUNKS;
    const int c = blk - b * CHUNKS;
    const int r = threadIdx.x;

    float w[N_IN];
#pragma unroll
    for (int i = 0; i < N_IN; ++i) w[i] = W_in[r * N_IN + i];

    const int t0 = c * BODY;
    const int tw = (t0 >= WARM) ? (t0 - WARM) : 0;
    const int nwarm = t0 - tw;

    const float4* xp4 = (const float4*)(xT + ((size_t)b * T_STEPS + tw) * 8);

    float v = 0.0f, cnt = 0.0f, vmax = -1e30f;

    // Warmup: recurrence only (no counting). Spike reset kept for principle.
    for (int t = 0; t < nwarm; ++t) {
        float4 a = xp4[2 * t];
        float4 d = xp4[2 * t + 1];
        float xp = w[0] * a.x + w[1] * a.y + w[2] * a.z + w[3] * a.w
                 + w[4] * d.x + w[5] * d.y + w[6] * d.z + w[7] * d.w;
        v = v + (xp - v) * 0.5f;
        float vm1 = v - 1.0f;
        vmax = fmaxf(vmax, vm1);
        v = (vm1 >= 0.0f) ? 0.0f : v;
    }

    // Body: count spikes.
    const float4* bp4 = xp4 + 2 * nwarm;
    for (int t = 0; t < BODY; ++t) {
        float4 a = bp4[2 * t];
        float4 d = bp4[2 * t + 1];
        float xp = w[0] * a.x + w[1] * a.y + w[2] * a.z + w[3] * a.w
                 + w[4] * d.x + w[5] * d.y + w[6] * d.z + w[7] * d.w;
        v = v + (xp - v) * 0.5f;
        float vm1 = v - 1.0f;
        vmax = fmaxf(vmax, vm1);
        bool s = (vm1 >= 0.0f);
        cnt += s ? 1.0f : 0.0f;
        v = s ? 0.0f : v;
    }

    partial[(size_t)blk * N_RES + r] = cnt;
    if (vmax >= -0.25f) atomicOr(flag, 1);   // v reached 0.75 somewhere
}

__global__ __launch_bounds__(256) void reduce_kernel(const float* __restrict__ partial,
                                                     float* __restrict__ out) {
    int idx = blockIdx.x * blockDim.x + threadIdx.x;  // b*512 + r
    int b = idx >> 9;
    int r = idx & (N_RES - 1);
    float s = 0.0f;
    for (int c = 0; c < CHUNKS; ++c)
        s += partial[((size_t)b * CHUNKS + c) * N_RES + r];
    out[idx] = s / (float)T_STEPS;
}

// Exact serial fallback (validated v2 structure). Runs the full recurrence
// only if flag != 0 (or unconditionally when flag == nullptr).
typedef float v2f __attribute__((ext_vector_type(2)));
typedef float v4f __attribute__((ext_vector_type(4)));

__global__ __launch_bounds__(64, 1) void reservoir_wave(
    const float* __restrict__ x,      // [B][N_IN][T]
    const float* __restrict__ W_in,   // [N_RES][N_IN]
    const float* __restrict__ W_rec,  // [N_RES][N_RES]
    const int* __restrict__ flag,
    float* __restrict__ out)          // [B][N_RES]
{
    if (flag && *flag == 0) return;

    __shared__ v4f xs4[2 * (T_STEPS + 1)];
    float* xsf = (float*)xs4;

    const int lane = threadIdx.x;
    const int b = blockIdx.x;

    const float* xb = x + (size_t)b * (N_IN * T_STEPS);
#pragma unroll
    for (int i = 0; i < N_IN; ++i)
        for (int t = lane; t < T_STEPS; t += 64)
            xsf[t * 8 + i] = xb[i * T_STEPS + t];
    if (lane < 8) xsf[T_STEPS * 8 + lane] = 0.0f;

    v2f w2[4][N_IN];
#pragma unroll
    for (int p = 0; p < 4; ++p) {
        const int r0 = (2 * p) * 64 + lane;
        const int r1 = r0 + 64;
#pragma unroll
        for (int i = 0; i < N_IN; ++i)
            w2[p][i] = (v2f){ W_in[r0 * N_IN + i], W_in[r1 * N_IN + i] };
    }

    v2f v[4], acc[4];
#pragma unroll
    for (int p = 0; p < 4; ++p) { v[p] = (v2f)0.0f; acc[p] = (v2f)0.0f; }

    unsigned long long mask[8];
#pragma unroll
    for (int k = 0; k < 8; ++k) mask[k] = 0ULL;

    __syncthreads();

    v4f xlo = xs4[0], xhi = xs4[1];

    for (int t = 0; t < T_STEPS; ++t) {
        v4f nlo = xs4[2 * t + 2];
        v4f nhi = xs4[2 * t + 3];

        v2f rec[4];
#pragma unroll
        for (int p = 0; p < 4; ++p) rec[p] = (v2f)0.0f;

        const unsigned long long anym =
            mask[0] | mask[1] | mask[2] | mask[3] |
            mask[4] | mask[5] | mask[6] | mask[7];
        if (anym) {
#pragma unroll
            for (int k2 = 0; k2 < 8; ++k2) {
                unsigned long long m = mask[k2];
                while (m) {
                    const int j = (k2 << 6) + __builtin_ctzll(m);
                    m &= m - 1;
#pragma unroll
                    for (int p = 0; p < 4; ++p) {
                        const int r0 = (2 * p) * 64 + lane;
                        rec[p].x += W_rec[(size_t)r0 * N_RES + j];
                        rec[p].y += W_rec[(size_t)(r0 + 64) * N_RES + j];
                    }
                }
            }
        }

        const float xf[8] = { xlo.x, xlo.y, xlo.z, xlo.w,
                              xhi.x, xhi.y, xhi.z, xhi.w };
        v2f xp[4];
#pragma unroll
        for (int p = 0; p < 4; ++p) xp[p] = rec[p];
#pragma unroll
        for (int i = 0; i < N_IN; ++i) {
            const v2f xv = (v2f){ xf[i], xf[i] };
#pragma unroll
            for (int p = 0; p < 4; ++p) xp[p] += w2[p][i] * xv;
        }

#pragma unroll
        for (int p = 0; p < 4; ++p) {
            v[p] = v[p] + (xp[p] - v[p]) * 0.5f;
            const bool s0 = (v[p].x - 1.0f) >= 0.0f;
            const bool s1 = (v[p].y - 1.0f) >= 0.0f;
            mask[2 * p]     = __ballot(s0);
            mask[2 * p + 1] = __ballot(s1);
            if (s0) { v[p].x = 0.0f; acc[p].x += 1.0f; }
            if (s1) { v[p].y = 0.0f; acc[p].y += 1.0f; }
        }

        xlo = nlo; xhi = nhi;
    }

#pragma unroll
    for (int p = 0; p < 4; ++p) {
        const int r0 = (2 * p) * 64 + lane;
        out[b * N_RES + r0]      = acc[p].x / (float)T_STEPS;
        out[b * N_RES + r0 + 64] = acc[p].y / (float)T_STEPS;
    }
}

extern "C" void kernel_launch(void* const* d_in, const int* in_sizes, int n_in,
                              void* d_out, int out_size, void* d_ws, size_t ws_size,
                              hipStream_t stream) {
    const float* x     = (const float*)d_in[0];   // 64*8*3000
    const float* W_in  = (const float*)d_in[1];   // 512*8
    const float* W_rec = (const float*)d_in[2];   // 512*512
    float* out = (float*)d_out;                   // 64*512

    const size_t xt_off = 256;
    const size_t xt_bytes = (size_t)B_SIZE * T_STEPS * N_IN * sizeof(float);   // 6.14 MB
    const size_t pt_off = xt_off + xt_bytes;
    const size_t pt_bytes = (size_t)B_SIZE * CHUNKS * N_RES * sizeof(float);   // 1.31 MB
    const size_t need = pt_off + pt_bytes;

    if (ws_size >= need) {
        int*   flag    = (int*)d_ws;
        float* xT      = (float*)((char*)d_ws + xt_off);
        float* partial = (float*)((char*)d_ws + pt_off);

        init_flag<<<1, 64, 0, stream>>>(flag);
        transpose_x<<<(B_SIZE * T_STEPS) / 256, 256, 0, stream>>>(x, xT);
        chunk_kernel<<<B_SIZE * CHUNKS, 512, 0, stream>>>(xT, W_in, partial, flag);
        reduce_kernel<<<(B_SIZE * N_RES) / 256, 256, 0, stream>>>(partial, out);
        // Exact serial recompute only if the guard tripped (v >= 0.75 anywhere).
        reservoir_wave<<<B_SIZE, 64, 0, stream>>>(x, W_in, W_rec, flag, out);
    } else {
        // Workspace too small for the parallel path: exact serial compute.
        reservoir_wave<<<B_SIZE, 64, 0, stream>>>(x, W_in, W_rec, nullptr, out);
    }
}

// Round 4
// 75.109 us; speedup vs baseline: 25.4902x; 1.4450x over previous
//
#include <hip/hip_runtime.h>

// SpikingReservoir v4: B=64, N_IN=8, T=3000, N_RES=512.
// Linear-filter reformulation: absent spikes, v[b,t,r] = W_in[r] . f[b,t]
// where f is the LIF IIR applied to the 8-channel input x. We:
//   1) filter x (8 ch/batch, chunked with 150-step warmup; state is dead
//      after ~150 steps since decay=0.5/step underflows f32),
//   2) scan all v = W.f tracking only max(v)  (no serial state at all),
//   3) if max(v) < 0.75 everywhere, the true system provably never spikes
//      -> output is exactly 0 (pre-zero-filled).
// Guard trip (v >= 0.75 anywhere, incl. any actual spike) -> exact serial
// fallback kernel (validated v2 structure) recomputes and overwrites out.
//
// ws layout: [int flag][pad to 256B][xf: B*T*8 f32 (6.14 MB)]

#define N_RES 512
#define N_IN 8
#define T_STEPS 3000
#define B_SIZE 64

#define FCHUNKS 8
#define FBODY 375          // 3000/8
#define FWARM 150

#define TSLICES 24
#define SLICE 125          // 3000/24

typedef float v2f __attribute__((ext_vector_type(2)));
typedef float v4f __attribute__((ext_vector_type(4)));

// flag = 0 and out = 0 (out is correct already unless the guard trips).
__global__ __launch_bounds__(256) void init_kernel(int* __restrict__ flag,
                                                   float* __restrict__ out) {
    int idx = blockIdx.x * blockDim.x + threadIdx.x;
    if (idx == 0) *flag = 0;
    if (idx < B_SIZE * N_RES) out[idx] = 0.0f;
}

// Per-channel LIF IIR: f <- f + (x_t - f)*0.5, written as xf[b][t][i].
// Thread = (b, chunk, channel); chunks warm up 150 steps from zero, which
// matches the serial filter to ~ulp (difference halves each step).
__global__ __launch_bounds__(256) void filter_x(const float* __restrict__ x,
                                                float* __restrict__ xf) {
    const int tid = blockIdx.x * blockDim.x + threadIdx.x;   // 0..4095
    const int i = tid & 7;
    const int c = (tid >> 3) & 7;
    const int b = tid >> 6;

    const int t0 = c * FBODY;
    const int tw = (t0 >= FWARM) ? (t0 - FWARM) : 0;

    const float* xs = x + ((size_t)b * N_IN + i) * T_STEPS;
    float f = 0.0f;
    for (int t = tw; t < t0; ++t) f += (xs[t] - f) * 0.5f;

    float* o = xf + (size_t)b * T_STEPS * 8 + i;
    for (int t = t0; t < t0 + FBODY; ++t) {
        f += (xs[t] - f) * 0.5f;
        o[(size_t)t * 8] = f;
    }
}

// Scan v[b,t,r] = W_in[r] . f[b,t] over a t-slice; track max only.
// 128 threads/block; thread owns 4 neurons (2x v2f -> v_pk_fma_f32).
__global__ __launch_bounds__(128) void guard_kernel(
    const float* __restrict__ xf,     // [B][T][8]
    const float* __restrict__ W_in,   // [N_RES][8]
    int* __restrict__ flag)
{
    __shared__ v4f xs4[SLICE * 2];    // 4000 B

    const int blk = blockIdx.x;       // b*TSLICES + sl
    const int b = blk / TSLICES;
    const int sl = blk - b * TSLICES;
    const int tid = threadIdx.x;      // 0..127

    // Stage this slice of xf (contiguous, coalesced 16B/lane).
    const v4f* src = (const v4f*)(xf + ((size_t)b * T_STEPS + sl * SLICE) * 8);
    for (int k = tid; k < SLICE * 2; k += 128) xs4[k] = src[k];

    // Neuron-pair weights: pair0 = (tid, tid+128), pair1 = (tid+256, tid+384).
    v2f w0[N_IN], w1[N_IN];
#pragma unroll
    for (int i = 0; i < N_IN; ++i) {
        w0[i] = (v2f){ W_in[(tid)       * N_IN + i], W_in[(tid + 128) * N_IN + i] };
        w1[i] = (v2f){ W_in[(tid + 256) * N_IN + i], W_in[(tid + 384) * N_IN + i] };
    }

    v2f vm0 = (v2f)(-1e30f), vm1 = (v2f)(-1e30f);
    __syncthreads();

#pragma unroll 2
    for (int t = 0; t < SLICE; ++t) {
        const v4f a = xs4[2 * t];          // broadcast ds_read_b128
        const v4f d = xs4[2 * t + 1];
        const float xff[8] = { a.x, a.y, a.z, a.w, d.x, d.y, d.z, d.w };
        v2f xp0 = (v2f)0.0f, xp1 = (v2f)0.0f;
#pragma unroll
        for (int i = 0; i < N_IN; ++i) {
            const v2f xv = (v2f){ xff[i], xff[i] };
            xp0 += w0[i] * xv;
            xp1 += w1[i] * xv;
        }
        vm0 = __builtin_elementwise_max(vm0, xp0);
        vm1 = __builtin_elementwise_max(vm1, xp1);
    }

    const v2f vm = __builtin_elementwise_max(vm0, vm1);
    if (fmaxf(vm.x, vm.y) >= 0.75f) atomicOr(flag, 1);
}

// ---- Exact serial fallback (validated v2 structure), gated on flag. ----
__global__ __launch_bounds__(64, 1) void reservoir_wave(
    const float* __restrict__ x,
    const float* __restrict__ W_in,
    const float* __restrict__ W_rec,
    const int* __restrict__ flag,
    float* __restrict__ out)
{
    if (flag && *flag == 0) return;

    __shared__ v4f xs4[2 * (T_STEPS + 1)];
    float* xsf = (float*)xs4;

    const int lane = threadIdx.x;
    const int b = blockIdx.x;

    const float* xb = x + (size_t)b * (N_IN * T_STEPS);
#pragma unroll
    for (int i = 0; i < N_IN; ++i)
        for (int t = lane; t < T_STEPS; t += 64)
            xsf[t * 8 + i] = xb[i * T_STEPS + t];
    if (lane < 8) xsf[T_STEPS * 8 + lane] = 0.0f;

    v2f w2[4][N_IN];
#pragma unroll
    for (int p = 0; p < 4; ++p) {
        const int r0 = (2 * p) * 64 + lane;
        const int r1 = r0 + 64;
#pragma unroll
        for (int i = 0; i < N_IN; ++i)
            w2[p][i] = (v2f){ W_in[r0 * N_IN + i], W_in[r1 * N_IN + i] };
    }

    v2f v[4], acc[4];
#pragma unroll
    for (int p = 0; p < 4; ++p) { v[p] = (v2f)0.0f; acc[p] = (v2f)0.0f; }

    unsigned long long mask[8];
#pragma unroll
    for (int k = 0; k < 8; ++k) mask[k] = 0ULL;

    __syncthreads();

    v4f xlo = xs4[0], xhi = xs4[1];

    for (int t = 0; t < T_STEPS; ++t) {
        v4f nlo = xs4[2 * t + 2];
        v4f nhi = xs4[2 * t + 3];

        v2f rec[4];
#pragma unroll
        for (int p = 0; p < 4; ++p) rec[p] = (v2f)0.0f;

        const unsigned long long anym =
            mask[0] | mask[1] | mask[2] | mask[3] |
            mask[4] | mask[5] | mask[6] | mask[7];
        if (anym) {
#pragma unroll
            for (int k2 = 0; k2 < 8; ++k2) {
                unsigned long long m = mask[k2];
                while (m) {
                    const int j = (k2 << 6) + __builtin_ctzll(m);
                    m &= m - 1;
#pragma unroll
                    for (int p = 0; p < 4; ++p) {
                        const int r0 = (2 * p) * 64 + lane;
                        rec[p].x += W_rec[(size_t)r0 * N_RES + j];
                        rec[p].y += W_rec[(size_t)(r0 + 64) * N_RES + j];
                    }
                }
            }
        }

        const float xff[8] = { xlo.x, xlo.y, xlo.z, xlo.w,
                               xhi.x, xhi.y, xhi.z, xhi.w };
        v2f xp[4];
#pragma unroll
        for (int p = 0; p < 4; ++p) xp[p] = rec[p];
#pragma unroll
        for (int i = 0; i < N_IN; ++i) {
            const v2f xv = (v2f){ xff[i], xff[i] };
#pragma unroll
            for (int p = 0; p < 4; ++p) xp[p] += w2[p][i] * xv;
        }

#pragma unroll
        for (int p = 0; p < 4; ++p) {
            v[p] = v[p] + (xp[p] - v[p]) * 0.5f;
            const bool s0 = (v[p].x - 1.0f) >= 0.0f;
            const bool s1 = (v[p].y - 1.0f) >= 0.0f;
            mask[2 * p]     = __ballot(s0);
            mask[2 * p + 1] = __ballot(s1);
            if (s0) { v[p].x = 0.0f; acc[p].x += 1.0f; }
            if (s1) { v[p].y = 0.0f; acc[p].y += 1.0f; }
        }

        xlo = nlo; xhi = nhi;
    }

#pragma unroll
    for (int p = 0; p < 4; ++p) {
        const int r0 = (2 * p) * 64 + lane;
        out[b * N_RES + r0]      = acc[p].x / (float)T_STEPS;
        out[b * N_RES + r0 + 64] = acc[p].y / (float)T_STEPS;
    }
}

extern "C" void kernel_launch(void* const* d_in, const int* in_sizes, int n_in,
                              void* d_out, int out_size, void* d_ws, size_t ws_size,
                              hipStream_t stream) {
    const float* x     = (const float*)d_in[0];   // 64*8*3000
    const float* W_in  = (const float*)d_in[1];   // 512*8
    const float* W_rec = (const float*)d_in[2];   // 512*512
    float* out = (float*)d_out;                   // 64*512

    const size_t xf_off = 256;
    const size_t xf_bytes = (size_t)B_SIZE * T_STEPS * N_IN * sizeof(float);  // 6.14 MB
    const size_t need = xf_off + xf_bytes;

    if (ws_size >= need) {
        int*   flag = (int*)d_ws;
        float* xf   = (float*)((char*)d_ws + xf_off);

        init_kernel<<<(B_SIZE * N_RES) / 256, 256, 0, stream>>>(flag, out);
        filter_x<<<(B_SIZE * N_IN * FCHUNKS) / 256, 256, 0, stream>>>(x, xf);
        guard_kernel<<<B_SIZE * TSLICES, 128, 0, stream>>>(xf, W_in, flag);
        // Exact serial recompute only if the guard tripped (v >= 0.75 anywhere).
        reservoir_wave<<<B_SIZE, 64, 0, stream>>>(x, W_in, W_rec, flag, out);
    } else {
        reservoir_wave<<<B_SIZE, 64, 0, stream>>>(x, W_in, W_rec, nullptr, out);
    }
}

// Round 5
// 46.174 us; speedup vs baseline: 41.4639x; 1.6267x over previous
//
#include <hip/hip_runtime.h>

// SpikingReservoir v5: B=64, N_IN=8, T=3000, N_RES=512.
// Fused filter+guard: absent spikes, v[b,t,r] = W_in[r] . f[b,t] where f is
// the per-channel LIF IIR of x (decay 0.5/step -> state memory dies in ~64
// steps to 5e-20 relative). Each (b, t-slice) block:
//   1) stages x[b][:, t0-64 .. t0+125) in LDS (coalesced),
//   2) 8 threads serially filter the 8 channels into LDS (warmup 64 from 0),
//   3) 128 threads scan v = W.f for 512 neurons x 125 steps, tracking max(v).
// If max(v) < 0.75 everywhere AND |f| <= 1e6 everywhere, the true system
// provably never spikes (0.25 threshold margin >> warmup error 0.5^64*1e6
// + reassociation error) -> output is exactly 0. Otherwise the finalize
// kernel runs the exact validated serial recurrence (v2 structure).
//
// ws layout: [int flag] only.

#define N_RES 512
#define N_IN 8
#define T_STEPS 3000
#define B_SIZE 64

#define SLICE 125
#define NSLICE 24          // 24*125 = 3000
#define GWARM 64

typedef float v2f __attribute__((ext_vector_type(2)));
typedef float v4f __attribute__((ext_vector_type(4)));

__global__ __launch_bounds__(64) void init_flag(int* __restrict__ flag) {
    if (threadIdx.x == 0) *flag = 0;
}

__global__ __launch_bounds__(128) void guard_fused(
    const float* __restrict__ x,      // [B][8][T]
    const float* __restrict__ W_in,   // [512][8]
    int* __restrict__ flag)
{
    __shared__ float xs[N_IN][SLICE + GWARM + 3];  // 8 x 192 staged input
    __shared__ v4f fs4[SLICE * 2];                 // filtered, [t][8] floats
    __shared__ int lflag;

    const int blk = blockIdx.x;        // b*NSLICE + sl
    const int b = blk / NSLICE;
    const int sl = blk - b * NSLICE;
    const int tid = threadIdx.x;       // 0..127

    const int t0 = sl * SLICE;
    const int tw = (t0 >= GWARM) ? (t0 - GWARM) : 0;
    const int nwarm = t0 - tw;         // 0 (first slice) or 64
    const int total = nwarm + SLICE;

    if (tid == 0) lflag = 0;

    // Stage x rows (each row contiguous in global -> coalesced).
    const float* xb = x + (size_t)b * (N_IN * T_STEPS) + tw;
#pragma unroll
    for (int i = 0; i < N_IN; ++i)
        for (int k = tid; k < total; k += 128)
            xs[i][k] = xb[i * T_STEPS + k];

    // Neuron weights: pair0 = (tid, tid+128), pair1 = (tid+256, tid+384).
    v2f w0[N_IN], w1[N_IN];
#pragma unroll
    for (int i = 0; i < N_IN; ++i) {
        w0[i] = (v2f){ W_in[(tid)       * N_IN + i], W_in[(tid + 128) * N_IN + i] };
        w1[i] = (v2f){ W_in[(tid + 256) * N_IN + i], W_in[(tid + 384) * N_IN + i] };
    }

    __syncthreads();

    // 8-thread serial filter: f <- f + (x - f)*0.5; track |f| blow-up.
    if (tid < N_IN) {
        float f = 0.0f, fmx = 0.0f;
        for (int k = 0; k < nwarm; ++k) {
            f += (xs[tid][k] - f) * 0.5f;
            fmx = fmaxf(fmx, fabsf(f));
        }
        float* fo = (float*)fs4 + tid;
        for (int k = 0; k < SLICE; ++k) {
            f += (xs[tid][nwarm + k] - f) * 0.5f;
            fmx = fmaxf(fmx, fabsf(f));
            fo[k * 8] = f;
        }
        if (fmx > 1e6f) atomicOr(&lflag, 1);
    }
    __syncthreads();

    // Guard scan: v = W.f, max over the slice (identical math to v4 guard).
    v2f vm0 = (v2f)(-1e30f), vm1 = (v2f)(-1e30f);
#pragma unroll 2
    for (int t = 0; t < SLICE; ++t) {
        const v4f a = fs4[2 * t];          // broadcast ds_read_b128
        const v4f d = fs4[2 * t + 1];
        const float xff[8] = { a.x, a.y, a.z, a.w, d.x, d.y, d.z, d.w };
        v2f xp0 = (v2f)0.0f, xp1 = (v2f)0.0f;
#pragma unroll
        for (int i = 0; i < N_IN; ++i) {
            const v2f xv = (v2f){ xff[i], xff[i] };
            xp0 += w0[i] * xv;
            xp1 += w1[i] * xv;
        }
        vm0 = __builtin_elementwise_max(vm0, xp0);
        vm1 = __builtin_elementwise_max(vm1, xp1);
    }
    const v2f vm = __builtin_elementwise_max(vm0, vm1);
    if (fmaxf(vm.x, vm.y) >= 0.75f) atomicOr(&lflag, 1);

    __syncthreads();
    if (tid == 0 && lflag) atomicOr(flag, 1);
}

// Finalize: flag==0 -> out is exactly 0. Else exact serial recompute
// (validated v2 wave kernel). flag==nullptr -> unconditional serial.
__global__ __launch_bounds__(64, 1) void finalize_kernel(
    const float* __restrict__ x,
    const float* __restrict__ W_in,
    const float* __restrict__ W_rec,
    const int* __restrict__ flag,
    float* __restrict__ out)
{
    const int lane = threadIdx.x;
    const int b = blockIdx.x;

    if (flag && *flag == 0) {
#pragma unroll
        for (int k = 0; k < 8; ++k)
            out[b * N_RES + k * 64 + lane] = 0.0f;
        return;
    }

    __shared__ v4f xs4[2 * (T_STEPS + 1)];
    float* xsf = (float*)xs4;

    const float* xb = x + (size_t)b * (N_IN * T_STEPS);
#pragma unroll
    for (int i = 0; i < N_IN; ++i)
        for (int t = lane; t < T_STEPS; t += 64)
            xsf[t * 8 + i] = xb[i * T_STEPS + t];
    if (lane < 8) xsf[T_STEPS * 8 + lane] = 0.0f;

    v2f w2[4][N_IN];
#pragma unroll
    for (int p = 0; p < 4; ++p) {
        const int r0 = (2 * p) * 64 + lane;
        const int r1 = r0 + 64;
#pragma unroll
        for (int i = 0; i < N_IN; ++i)
            w2[p][i] = (v2f){ W_in[r0 * N_IN + i], W_in[r1 * N_IN + i] };
    }

    v2f v[4], acc[4];
#pragma unroll
    for (int p = 0; p < 4; ++p) { v[p] = (v2f)0.0f; acc[p] = (v2f)0.0f; }

    unsigned long long mask[8];
#pragma unroll
    for (int k = 0; k < 8; ++k) mask[k] = 0ULL;

    __syncthreads();

    v4f xlo = xs4[0], xhi = xs4[1];

    for (int t = 0; t < T_STEPS; ++t) {
        v4f nlo = xs4[2 * t + 2];
        v4f nhi = xs4[2 * t + 3];

        v2f rec[4];
#pragma unroll
        for (int p = 0; p < 4; ++p) rec[p] = (v2f)0.0f;

        const unsigned long long anym =
            mask[0] | mask[1] | mask[2] | mask[3] |
            mask[4] | mask[5] | mask[6] | mask[7];
        if (anym) {
#pragma unroll
            for (int k2 = 0; k2 < 8; ++k2) {
                unsigned long long m = mask[k2];
                while (m) {
                    const int j = (k2 << 6) + __builtin_ctzll(m);
                    m &= m - 1;
#pragma unroll
                    for (int p = 0; p < 4; ++p) {
                        const int r0 = (2 * p) * 64 + lane;
                        rec[p].x += W_rec[(size_t)r0 * N_RES + j];
                        rec[p].y += W_rec[(size_t)(r0 + 64) * N_RES + j];
                    }
                }
            }
        }

        const float xff[8] = { xlo.x, xlo.y, xlo.z, xlo.w,
                               xhi.x, xhi.y, xhi.z, xhi.w };
        v2f xp[4];
#pragma unroll
        for (int p = 0; p < 4; ++p) xp[p] = rec[p];
#pragma unroll
        for (int i = 0; i < N_IN; ++i) {
            const v2f xv = (v2f){ xff[i], xff[i] };
#pragma unroll
            for (int p = 0; p < 4; ++p) xp[p] += w2[p][i] * xv;
        }

#pragma unroll
        for (int p = 0; p < 4; ++p) {
            v[p] = v[p] + (xp[p] - v[p]) * 0.5f;
            const bool s0 = (v[p].x - 1.0f) >= 0.0f;
            const bool s1 = (v[p].y - 1.0f) >= 0.0f;
            mask[2 * p]     = __ballot(s0);
            mask[2 * p + 1] = __ballot(s1);
            if (s0) { v[p].x = 0.0f; acc[p].x += 1.0f; }
            if (s1) { v[p].y = 0.0f; acc[p].y += 1.0f; }
        }

        xlo = nlo; xhi = nhi;
    }

#pragma unroll
    for (int p = 0; p < 4; ++p) {
        const int r0 = (2 * p) * 64 + lane;
        out[b * N_RES + r0]      = acc[p].x / (float)T_STEPS;
        out[b * N_RES + r0 + 64] = acc[p].y / (float)T_STEPS;
    }
}

extern "C" void kernel_launch(void* const* d_in, const int* in_sizes, int n_in,
                              void* d_out, int out_size, void* d_ws, size_t ws_size,
                              hipStream_t stream) {
    const float* x     = (const float*)d_in[0];   // 64*8*3000
    const float* W_in  = (const float*)d_in[1];   // 512*8
    const float* W_rec = (const float*)d_in[2];   // 512*512
    float* out = (float*)d_out;                   // 64*512

    if (ws_size >= sizeof(int)) {
        int* flag = (int*)d_ws;
        init_flag<<<1, 64, 0, stream>>>(flag);
        guard_fused<<<B_SIZE * NSLICE, 128, 0, stream>>>(x, W_in, flag);
        finalize_kernel<<<B_SIZE, 64, 0, stream>>>(x, W_in, W_rec, flag, out);
    } else {
        finalize_kernel<<<B_SIZE, 64, 0, stream>>>(x, W_in, W_rec, nullptr, out);
    }
}

// Round 6
// 31.465 us; speedup vs baseline: 60.8467x; 1.4675x over previous
//
#include <hip/hip_runtime.h>

// SpikingReservoir v6: B=64, N_IN=8, T=3000, N_RES=512.
// Guard via Cauchy-Schwarz: max_r W_r.f <= ||f|| * max_r||W_r||. Per-t work
// collapses from 512 dots to one 8-dim norm. Lane = 13-step time chunk
// (13 coprime 32 -> conflict-free LDS stride), 48-step warmup from zero
// (decay 0.5/step; error 0.5^48*|x|, with |x|<=1e5 enforced by sanity flag).
// Rare norm failures get an in-wave cooperative EXACT 512-dot check, so the
// fallback flag trips only if some v >= 0.75 (same guarantee as v5's guard,
// validated twice). flags[256] slots are plain-stored by each block every
// call -> self-resetting, no init kernel. Finalize ORs flags: 0 -> out = 0
// exactly; else exact serial recurrence (validated v2 wave kernel).
//
// ws layout: int flags[256] (1 KB).

#define N_RES 512
#define N_IN 8
#define T_STEPS 3000
#define B_SIZE 64

#define WARM 48
#define BODY 13                 // coprime with 32 -> 2-way LDS alias (free)
#define SPAN (64 * BODY)        // 832 steps per block
#define NQ 4                    // 4*832 = 3328 >= 3000
#define XMAX (WARM + SPAN)      // 880
#define THR2 0.5625f            // 0.75^2
#define XSANE 1e5f              // |x| bound for the error-margin argument

typedef float v2f __attribute__((ext_vector_type(2)));
typedef float v4f __attribute__((ext_vector_type(4)));

__global__ __launch_bounds__(64) void guard_kernel(
    const float* __restrict__ x,      // [B][8][T]
    const float* __restrict__ W_in,   // [512][8]
    int* __restrict__ flags)          // [256]
{
    __shared__ float xs[N_IN][XMAX];  // 28.2 KB

    const int blk = blockIdx.x;       // b*NQ + q
    const int b = blk >> 2;
    const int q = blk & 3;
    const int lane = threadIdx.x;     // 0..63

    const int blk_s = q * SPAN;
    const int blk_e = min(T_STEPS, blk_s + SPAN);
    const int ws_s = (blk_s >= WARM) ? (blk_s - WARM) : 0;
    const int len = blk_e - ws_s;     // <= 880

    // M2 = max_r ||W_r||^2 (computed per block; 16 KB of W is L2-hot).
    float m2 = 0.0f;
    bool m2nan = false;
#pragma unroll
    for (int n = 0; n < 8; ++n) {
        const int r = lane + (n << 6);
        const float4 wa = *(const float4*)(W_in + r * 8);
        const float4 wb = *(const float4*)(W_in + r * 8 + 4);
        const float s = wa.x * wa.x + wa.y * wa.y + wa.z * wa.z + wa.w * wa.w
                      + wb.x * wb.x + wb.y * wb.y + wb.z * wb.z + wb.w * wb.w;
        m2nan |= (s != s);
        m2 = fmaxf(m2, s);
    }
#pragma unroll
    for (int off = 32; off >= 1; off >>= 1)
        m2 = fmaxf(m2, __shfl_xor(m2, off));
    m2 = __any(m2nan) ? __builtin_inff() : m2 * 1.00001f;

    // Stage x window (coalesced per channel row) + sanity check.
    bool bad = false;
    const float* xb = x + (size_t)b * (N_IN * T_STEPS);
#pragma unroll
    for (int i = 0; i < N_IN; ++i)
        for (int k = lane; k < len; k += 64) {
            const float v = xb[i * T_STEPS + ws_s + k];
            bad |= !(fabsf(v) <= XSANE);  // catches inf/NaN/huge -> fallback
            xs[i][k] = v;
        }

    // Lane's chunk: body steps [s0, se), warmup from tw.
    const int s0 = blk_s + lane * BODY;
    const int se = min(s0 + BODY, T_STEPS);
    const int tw = (s0 >= WARM) ? (s0 - WARM) : 0;
    const int nst = (s0 < T_STEPS) ? (se - tw) : 0;
    const int nwarm = s0 - tw;
    const int loc = tw - ws_s;

    __syncthreads();

    // Main scan: filter 8 channels (4x packed v2f IIRs), track max ||f||^2
    // over body steps.
    v2f f01 = (v2f)0.f, f23 = (v2f)0.f, f45 = (v2f)0.f, f67 = (v2f)0.f;
    float nmax = 0.0f;
    for (int k = 0; k < nst; ++k) {
        const int u = loc + k;
        const v2f x01 = (v2f){ xs[0][u], xs[1][u] };
        const v2f x23 = (v2f){ xs[2][u], xs[3][u] };
        const v2f x45 = (v2f){ xs[4][u], xs[5][u] };
        const v2f x67 = (v2f){ xs[6][u], xs[7][u] };
        f01 += (x01 - f01) * 0.5f;
        f23 += (x23 - f23) * 0.5f;
        f45 += (x45 - f45) * 0.5f;
        f67 += (x67 - f67) * 0.5f;
        v2f p = f01 * f01;
        p += f23 * f23;
        p += f45 * f45;
        p += f67 * f67;
        const float n2 = p.x + p.y;
        if (k >= nwarm) nmax = fmaxf(nmax, n2);
    }

    const bool fail = !(nmax * m2 < THR2);   // NaN-safe: NaN -> true
    if (__any(fail)) {
        // Rare path: replay, and at each failing step do a wave-cooperative
        // EXACT max_r W_r.f check (8 neurons per lane).
        v2f g01 = (v2f)0.f, g23 = (v2f)0.f, g45 = (v2f)0.f, g67 = (v2f)0.f;
        for (int k = 0; k < WARM + BODY; ++k) {
            bool mybad = false;
            if (k < nst) {
                const int u = loc + k;
                const v2f x01 = (v2f){ xs[0][u], xs[1][u] };
                const v2f x23 = (v2f){ xs[2][u], xs[3][u] };
                const v2f x45 = (v2f){ xs[4][u], xs[5][u] };
                const v2f x67 = (v2f){ xs[6][u], xs[7][u] };
                g01 += (x01 - g01) * 0.5f;
                g23 += (x23 - g23) * 0.5f;
                g45 += (x45 - g45) * 0.5f;
                g67 += (x67 - g67) * 0.5f;
                v2f p = g01 * g01;
                p += g23 * g23;
                p += g45 * g45;
                p += g67 * g67;
                const float n2 = p.x + p.y;
                mybad = (k >= nwarm) && !(n2 * m2 < THR2);
            }
            unsigned long long bal = __ballot(mybad);
            while (bal) {
                const int l = (int)__builtin_ctzll(bal);
                bal &= bal - 1;
                float h[8];
                h[0] = __shfl(g01.x, l); h[1] = __shfl(g01.y, l);
                h[2] = __shfl(g23.x, l); h[3] = __shfl(g23.y, l);
                h[4] = __shfl(g45.x, l); h[5] = __shfl(g45.y, l);
                h[6] = __shfl(g67.x, l); h[7] = __shfl(g67.y, l);
                float vmx = -1e30f;
#pragma unroll
                for (int n = 0; n < 8; ++n) {
                    const float* wr = W_in + (lane * 8 + n) * 8;
                    float d = 0.f;
#pragma unroll
                    for (int i = 0; i < N_IN; ++i) d += wr[i] * h[i];
                    vmx = fmaxf(vmx, d);
                }
#pragma unroll
                for (int off = 32; off >= 1; off >>= 1)
                    vmx = fmaxf(vmx, __shfl_xor(vmx, off));
                bad |= !(vmx < 0.75f);
                // NaN dots correspond to NaN v_true, which never satisfies
                // (v-1 >= 0) in the reference -> safe if fmax drops them.
            }
        }
    }

    const int myflag = __any(bad) ? 1 : 0;
    if (lane == 0) flags[blk] = myflag;
}

// Finalize: OR the 256 block flags. 0 -> out is exactly 0. Else exact serial
// recompute (validated v2 wave kernel). flags==nullptr -> unconditional serial.
__global__ __launch_bounds__(64, 1) void finalize_kernel(
    const float* __restrict__ x,
    const float* __restrict__ W_in,
    const float* __restrict__ W_rec,
    const int* __restrict__ flags,
    float* __restrict__ out)
{
    const int lane = threadIdx.x;
    const int b = blockIdx.x;

    bool trip = true;
    if (flags) {
        int s = 0;
        for (int i = lane; i < B_SIZE * NQ; i += 64) s |= flags[i];
        trip = __any(s != 0);
    }
    if (!trip) {
#pragma unroll
        for (int k = 0; k < 8; ++k)
            out[b * N_RES + k * 64 + lane] = 0.0f;
        return;
    }

    __shared__ v4f xs4[2 * (T_STEPS + 1)];
    float* xsf = (float*)xs4;

    const float* xb = x + (size_t)b * (N_IN * T_STEPS);
#pragma unroll
    for (int i = 0; i < N_IN; ++i)
        for (int t = lane; t < T_STEPS; t += 64)
            xsf[t * 8 + i] = xb[i * T_STEPS + t];
    if (lane < 8) xsf[T_STEPS * 8 + lane] = 0.0f;

    v2f w2[4][N_IN];
#pragma unroll
    for (int p = 0; p < 4; ++p) {
        const int r0 = (2 * p) * 64 + lane;
        const int r1 = r0 + 64;
#pragma unroll
        for (int i = 0; i < N_IN; ++i)
            w2[p][i] = (v2f){ W_in[r0 * N_IN + i], W_in[r1 * N_IN + i] };
    }

    v2f v[4], acc[4];
#pragma unroll
    for (int p = 0; p < 4; ++p) { v[p] = (v2f)0.0f; acc[p] = (v2f)0.0f; }

    unsigned long long mask[8];
#pragma unroll
    for (int k = 0; k < 8; ++k) mask[k] = 0ULL;

    __syncthreads();

    v4f xlo = xs4[0], xhi = xs4[1];

    for (int t = 0; t < T_STEPS; ++t) {
        v4f nlo = xs4[2 * t + 2];
        v4f nhi = xs4[2 * t + 3];

        v2f rec[4];
#pragma unroll
        for (int p = 0; p < 4; ++p) rec[p] = (v2f)0.0f;

        const unsigned long long anym =
            mask[0] | mask[1] | mask[2] | mask[3] |
            mask[4] | mask[5] | mask[6] | mask[7];
        if (anym) {
#pragma unroll
            for (int k2 = 0; k2 < 8; ++k2) {
                unsigned long long m = mask[k2];
                while (m) {
                    const int j = (k2 << 6) + __builtin_ctzll(m);
                    m &= m - 1;
#pragma unroll
                    for (int p = 0; p < 4; ++p) {
                        const int r0 = (2 * p) * 64 + lane;
                        rec[p].x += W_rec[(size_t)r0 * N_RES + j];
                        rec[p].y += W_rec[(size_t)(r0 + 64) * N_RES + j];
                    }
                }
            }
        }

        const float xff[8] = { xlo.x, xlo.y, xlo.z, xlo.w,
                               xhi.x, xhi.y, xhi.z, xhi.w };
        // Reference order: input projection first, then + recurrent.
        v2f xp[4];
#pragma unroll
        for (int p = 0; p < 4; ++p) xp[p] = (v2f)0.0f;
#pragma unroll
        for (int i = 0; i < N_IN; ++i) {
            const v2f xv = (v2f){ xff[i], xff[i] };
#pragma unroll
            for (int p = 0; p < 4; ++p) xp[p] += w2[p][i] * xv;
        }
#pragma unroll
        for (int p = 0; p < 4; ++p) xp[p] += rec[p];

#pragma unroll
        for (int p = 0; p < 4; ++p) {
            v[p] = v[p] + (xp[p] - v[p]) * 0.5f;
            const bool s0 = (v[p].x - 1.0f) >= 0.0f;
            const bool s1 = (v[p].y - 1.0f) >= 0.0f;
            mask[2 * p]     = __ballot(s0);
            mask[2 * p + 1] = __ballot(s1);
            if (s0) { v[p].x = 0.0f; acc[p].x += 1.0f; }
            if (s1) { v[p].y = 0.0f; acc[p].y += 1.0f; }
        }

        xlo = nlo; xhi = nhi;
    }

#pragma unroll
    for (int p = 0; p < 4; ++p) {
        const int r0 = (2 * p) * 64 + lane;
        out[b * N_RES + r0]      = acc[p].x / (float)T_STEPS;
        out[b * N_RES + r0 + 64] = acc[p].y / (float)T_STEPS;
    }
}

extern "C" void kernel_launch(void* const* d_in, const int* in_sizes, int n_in,
                              void* d_out, int out_size, void* d_ws, size_t ws_size,
                              hipStream_t stream) {
    const float* x     = (const float*)d_in[0];   // 64*8*3000
    const float* W_in  = (const float*)d_in[1];   // 512*8
    const float* W_rec = (const float*)d_in[2];   // 512*512
    float* out = (float*)d_out;                   // 64*512

    const size_t need = (size_t)(B_SIZE * NQ) * sizeof(int);   // 1 KB

    if (ws_size >= need) {
        int* flags = (int*)d_ws;
        guard_kernel<<<B_SIZE * NQ, 64, 0, stream>>>(x, W_in, flags);
        finalize_kernel<<<B_SIZE, 64, 0, stream>>>(x, W_in, W_rec, flags, out);
    } else {
        finalize_kernel<<<B_SIZE, 64, 0, stream>>>(x, W_in, W_rec, nullptr, out);
    }
}

// Round 7
// 15.006 us; speedup vs baseline: 127.5882x; 2.0969x over previous
//
#include <hip/hip_runtime.h>

// SpikingReservoir v7: B=64, N_IN=8, T=3000, N_RES=512.
// Wave-parallel filter scan. The LIF input filter f_t = 0.5 f_{t-1} + 0.5 x_t
// is linear -> Kogge-Stone inclusive scan across 64 lanes (6 shfl_up steps
// with per-lane masked coefficients 0.5^d), carry chained across 64-step
// tiles. No LDS, loads directly coalesced. 16 spans/batch x 4 tiles = 1024
// waves. Guard: per-tile Cauchy-Schwarz norm test ||f||^2 * max_r||W_r||^2 <
// 0.75^2; rare failures -> in-wave cooperative EXACT 512-dot check (v6-
// validated logic). Sanity bounds |x|<=1e3, m2<=100 keep the total
// warmup(0.5^24)+rounding error in v below ~0.06 << the 0.25 threshold
// margin for ANY input. flags[1024] plain-stored every call (self-reset).
// Finalize: all flags 0 -> provably spike-free -> out = 0 exactly; else
// exact serial recurrence (validated v2 wave kernel).
//
// ws layout: int flags[1024] (4 KB).

#define N_RES 512
#define N_IN 8
#define T_STEPS 3000
#define B_SIZE 64

#define NQ 16               // spans per batch
#define SPAN 188            // 16*188 = 3008 >= 3000
#define WARM 24             // warmup steps; 0.5^24 * 1e3 = 6e-5
#define TILES 4             // 4*64 = 256 >= 188+24
#define THR2 0.5625f        // 0.75^2
#define XSANE 1e3f
#define M2SANE 100.0f

typedef float v2f __attribute__((ext_vector_type(2)));
typedef float v4f __attribute__((ext_vector_type(4)));

__global__ __launch_bounds__(64) void guard_scan(
    const float* __restrict__ x,      // [B][8][T]
    const float* __restrict__ W_in,   // [512][8]
    int* __restrict__ flags)          // [1024]
{
    const int lane = threadIdx.x;     // 0..63
    const int blk = blockIdx.x;       // b*NQ + q
    const int b = blk >> 4;
    const int q = blk & 15;

    // wmax2 = max_r ||W_r||^2 over all 512 rows (16 KB, L2-hot).
    float wmax2 = 0.0f;
#pragma unroll
    for (int n = 0; n < 8; ++n) {
        const int r = lane + (n << 6);
        const float4 wa = *(const float4*)(W_in + r * 8);
        const float4 wb = *(const float4*)(W_in + r * 8 + 4);
        const float s = wa.x * wa.x + wa.y * wa.y + wa.z * wa.z + wa.w * wa.w
                      + wb.x * wb.x + wb.y * wb.y + wb.z * wb.z + wb.w * wb.w;
        wmax2 = fmaxf(wmax2, s);
    }
#pragma unroll
    for (int off = 32; off >= 1; off >>= 1)
        wmax2 = fmaxf(wmax2, __shfl_xor(wmax2, off));
    bool bad = !(wmax2 <= M2SANE);     // NaN-safe sanity on weights
    wmax2 *= 1.00001f;

    const int body_lo = q * SPAN;
    const int body_hi = min(T_STEPS, body_lo + SPAN);
    const int tw = (body_lo >= WARM) ? (body_lo - WARM) : 0;

    const float* xb = x + (size_t)b * (N_IN * T_STEPS);

    // Per-lane constants: carry decay 0.5^(lane+1); scan coeffs 0.5^d masked.
    const float dec = __builtin_ldexpf(1.0f, -(lane + 1));
    const float c1  = (lane >= 1)  ? 0.5f       : 0.0f;
    const float c2  = (lane >= 2)  ? 0.25f      : 0.0f;
    const float c4  = (lane >= 4)  ? 0.0625f    : 0.0f;
    const float c8  = (lane >= 8)  ? 3.90625e-3f : 0.0f;   // 0.5^8
    const float c16 = (lane >= 16) ? 1.52587890625e-5f : 0.0f;  // 0.5^16
    const float c32 = (lane >= 32) ? 2.3283064365386963e-10f : 0.0f; // 0.5^32

    v2f fc01 = (v2f)0.f, fc23 = (v2f)0.f, fc45 = (v2f)0.f, fc67 = (v2f)0.f;

    // Prefetched tile loads.
    float cur[8], nxt[8];
    {
        const int tc = min(tw + lane, T_STEPS - 1);
#pragma unroll
        for (int i = 0; i < N_IN; ++i) cur[i] = xb[i * T_STEPS + tc];
    }

#pragma unroll
    for (int tile = 0; tile < TILES; ++tile) {
        if (tile < TILES - 1) {
            const int tc = min(tw + (tile + 1) * 64 + lane, T_STEPS - 1);
#pragma unroll
            for (int i = 0; i < N_IN; ++i) nxt[i] = xb[i * T_STEPS + tc];
        }

#pragma unroll
        for (int i = 0; i < N_IN; ++i) bad |= !(fabsf(cur[i]) <= XSANE);

        // Scan init: B = 0.5 * x_t per channel (4x v2f).
        v2f B01 = (v2f){ cur[0], cur[1] } * 0.5f;
        v2f B23 = (v2f){ cur[2], cur[3] } * 0.5f;
        v2f B45 = (v2f){ cur[4], cur[5] } * 0.5f;
        v2f B67 = (v2f){ cur[6], cur[7] } * 0.5f;

        // Kogge-Stone: B_l += 0.5^d * B_{l-d} (masked for l < d).
#define SCAN_STEP(D, C)                                                  \
        {                                                                \
            v2f s01, s23, s45, s67;                                      \
            s01.x = __shfl_up(B01.x, D); s01.y = __shfl_up(B01.y, D);    \
            s23.x = __shfl_up(B23.x, D); s23.y = __shfl_up(B23.y, D);    \
            s45.x = __shfl_up(B45.x, D); s45.y = __shfl_up(B45.y, D);    \
            s67.x = __shfl_up(B67.x, D); s67.y = __shfl_up(B67.y, D);    \
            const v2f cc = (v2f){ C, C };                                \
            B01 += s01 * cc; B23 += s23 * cc;                            \
            B45 += s45 * cc; B67 += s67 * cc;                            \
        }
        SCAN_STEP(1, c1)
        SCAN_STEP(2, c2)
        SCAN_STEP(4, c4)
        SCAN_STEP(8, c8)
        SCAN_STEP(16, c16)
        SCAN_STEP(32, c32)
#undef SCAN_STEP

        // Add carry: f_l = B_l + 0.5^(l+1) * f_carry.
        const v2f dd = (v2f){ dec, dec };
        B01 += fc01 * dd; B23 += fc23 * dd;
        B45 += fc45 * dd; B67 += fc67 * dd;

        // New carry = f at lane 63.
        fc01.x = __shfl(B01.x, 63); fc01.y = __shfl(B01.y, 63);
        fc23.x = __shfl(B23.x, 63); fc23.y = __shfl(B23.y, 63);
        fc45.x = __shfl(B45.x, 63); fc45.y = __shfl(B45.y, 63);
        fc67.x = __shfl(B67.x, 63); fc67.y = __shfl(B67.y, 63);

        // Norm test on body lanes.
        v2f p = B01 * B01;
        p += B23 * B23;
        p += B45 * B45;
        p += B67 * B67;
        const float n2 = p.x + p.y;
        const int gt = tw + tile * 64 + lane;
        const bool inb = (gt >= body_lo) && (gt < body_hi);
        const bool fail = inb && !(n2 * wmax2 < THR2);   // NaN -> fail

        if (__any(fail)) {
            // Rare path: exact max_r W_r.f for each failing lane's f.
            unsigned long long bal = __ballot(fail);
            while (bal) {
                const int l = (int)__builtin_ctzll(bal);
                bal &= bal - 1;
                float h[8];
                h[0] = __shfl(B01.x, l); h[1] = __shfl(B01.y, l);
                h[2] = __shfl(B23.x, l); h[3] = __shfl(B23.y, l);
                h[4] = __shfl(B45.x, l); h[5] = __shfl(B45.y, l);
                h[6] = __shfl(B67.x, l); h[7] = __shfl(B67.y, l);
                float vmx = -1e30f;
#pragma unroll
                for (int n = 0; n < 8; ++n) {
                    const float* wr = W_in + (lane * 8 + n) * 8;
                    float d = 0.f;
#pragma unroll
                    for (int i = 0; i < N_IN; ++i) d += wr[i] * h[i];
                    vmx = fmaxf(vmx, d);
                }
#pragma unroll
                for (int off = 32; off >= 1; off >>= 1)
                    vmx = fmaxf(vmx, __shfl_xor(vmx, off));
                bad |= !(vmx < 0.75f);
            }
        }

#pragma unroll
        for (int i = 0; i < N_IN; ++i) cur[i] = nxt[i];
    }

    const int myflag = __any(bad) ? 1 : 0;
    if (lane == 0) flags[blk] = myflag;
}

// Finalize: OR the 1024 block flags. 0 -> out is exactly 0. Else exact serial
// recompute (validated v2 wave kernel). flags==nullptr -> unconditional serial.
__global__ __launch_bounds__(64, 1) void finalize_kernel(
    const float* __restrict__ x,
    const float* __restrict__ W_in,
    const float* __restrict__ W_rec,
    const int* __restrict__ flags,
    float* __restrict__ out)
{
    const int lane = threadIdx.x;
    const int b = blockIdx.x;

    bool trip = true;
    if (flags) {
        int s = 0;
        for (int i = lane; i < B_SIZE * NQ; i += 64) s |= flags[i];
        trip = __any(s != 0);
    }
    if (!trip) {
#pragma unroll
        for (int k = 0; k < 8; ++k)
            out[b * N_RES + k * 64 + lane] = 0.0f;
        return;
    }

    __shared__ v4f xs4[2 * (T_STEPS + 1)];
    float* xsf = (float*)xs4;

    const float* xb = x + (size_t)b * (N_IN * T_STEPS);
#pragma unroll
    for (int i = 0; i < N_IN; ++i)
        for (int t = lane; t < T_STEPS; t += 64)
            xsf[t * 8 + i] = xb[i * T_STEPS + t];
    if (lane < 8) xsf[T_STEPS * 8 + lane] = 0.0f;

    v2f w2[4][N_IN];
#pragma unroll
    for (int p = 0; p < 4; ++p) {
        const int r0 = (2 * p) * 64 + lane;
        const int r1 = r0 + 64;
#pragma unroll
        for (int i = 0; i < N_IN; ++i)
            w2[p][i] = (v2f){ W_in[r0 * N_IN + i], W_in[r1 * N_IN + i] };
    }

    v2f v[4], acc[4];
#pragma unroll
    for (int p = 0; p < 4; ++p) { v[p] = (v2f)0.0f; acc[p] = (v2f)0.0f; }

    unsigned long long mask[8];
#pragma unroll
    for (int k = 0; k < 8; ++k) mask[k] = 0ULL;

    __syncthreads();

    v4f xlo = xs4[0], xhi = xs4[1];

    for (int t = 0; t < T_STEPS; ++t) {
        v4f nlo = xs4[2 * t + 2];
        v4f nhi = xs4[2 * t + 3];

        v2f rec[4];
#pragma unroll
        for (int p = 0; p < 4; ++p) rec[p] = (v2f)0.0f;

        const unsigned long long anym =
            mask[0] | mask[1] | mask[2] | mask[3] |
            mask[4] | mask[5] | mask[6] | mask[7];
        if (anym) {
#pragma unroll
            for (int k2 = 0; k2 < 8; ++k2) {
                unsigned long long m = mask[k2];
                while (m) {
                    const int j = (k2 << 6) + __builtin_ctzll(m);
                    m &= m - 1;
#pragma unroll
                    for (int p = 0; p < 4; ++p) {
                        const int r0 = (2 * p) * 64 + lane;
                        rec[p].x += W_rec[(size_t)r0 * N_RES + j];
                        rec[p].y += W_rec[(size_t)(r0 + 64) * N_RES + j];
                    }
                }
            }
        }

        const float xff[8] = { xlo.x, xlo.y, xlo.z, xlo.w,
                               xhi.x, xhi.y, xhi.z, xhi.w };
        v2f xp[4];
#pragma unroll
        for (int p = 0; p < 4; ++p) xp[p] = (v2f)0.0f;
#pragma unroll
        for (int i = 0; i < N_IN; ++i) {
            const v2f xv = (v2f){ xff[i], xff[i] };
#pragma unroll
            for (int p = 0; p < 4; ++p) xp[p] += w2[p][i] * xv;
        }
#pragma unroll
        for (int p = 0; p < 4; ++p) xp[p] += rec[p];

#pragma unroll
        for (int p = 0; p < 4; ++p) {
            v[p] = v[p] + (xp[p] - v[p]) * 0.5f;
            const bool s0 = (v[p].x - 1.0f) >= 0.0f;
            const bool s1 = (v[p].y - 1.0f) >= 0.0f;
            mask[2 * p]     = __ballot(s0);
            mask[2 * p + 1] = __ballot(s1);
            if (s0) { v[p].x = 0.0f; acc[p].x += 1.0f; }
            if (s1) { v[p].y = 0.0f; acc[p].y += 1.0f; }
        }

        xlo = nlo; xhi = nhi;
    }

#pragma unroll
    for (int p = 0; p < 4; ++p) {
        const int r0 = (2 * p) * 64 + lane;
        out[b * N_RES + r0]      = acc[p].x / (float)T_STEPS;
        out[b * N_RES + r0 + 64] = acc[p].y / (float)T_STEPS;
    }
}

extern "C" void kernel_launch(void* const* d_in, const int* in_sizes, int n_in,
                              void* d_out, int out_size, void* d_ws, size_t ws_size,
                              hipStream_t stream) {
    const float* x     = (const float*)d_in[0];   // 64*8*3000
    const float* W_in  = (const float*)d_in[1];   // 512*8
    const float* W_rec = (const float*)d_in[2];   // 512*512
    float* out = (float*)d_out;                   // 64*512

    const size_t need = (size_t)(B_SIZE * NQ) * sizeof(int);   // 4 KB

    if (ws_size >= need) {
        int* flags = (int*)d_ws;
        guard_scan<<<B_SIZE * NQ, 64, 0, stream>>>(x, W_in, flags);
        finalize_kernel<<<B_SIZE, 64, 0, stream>>>(x, W_in, W_rec, flags, out);
    } else {
        finalize_kernel<<<B_SIZE, 64, 0, stream>>>(x, W_in, W_rec, nullptr, out);
    }
}

// Round 8
// 12.890 us; speedup vs baseline: 148.5290x; 1.1641x over previous
//
#include <hip/hip_runtime.h>

// SpikingReservoir v8: B=64, N_IN=8, T=3000, N_RES=512. ONE kernel.
// Block = batch (64 blocks x 768 threads = 12 waves). Wave q guards body
// steps [256q, 256q+256) via a 512-step window [256(q-1), 256q+256):
//  - lane owns 8 consecutive steps: local serial LIF-IIR (exact recurrence),
//  - lane-aggregate scan with ratio r = 0.5^8: only 2 Kogge-Stone steps + 1
//    carry shfl needed (r^4 ~ 2.3e-10 -> truncation error <= 2.3e-10*|x|;
//    window-start carry=0 is EXACT since 0.5^256 underflows to 0),
//  - Cauchy-Schwarz test ||f||^2 * max_r||W_r||^2 < 0.75^2 per step,
//  - rare failures: in-wave cooperative EXACT max_r W_r.f check (v6/v7-
//    validated logic; this path is live - the norm bound alone is loose).
// Sanity bounds |x|<=1e3, max||W_r||^2<=100 keep total scan/warmup error in
// v below ~0.11 << the 0.25 threshold margin for ANY input. Block-local LDS
// flag; if clear -> out[b] = 0 exactly (provably spike-free); else in-block
// exact serial recurrence (validated v2 wave structure). No workspace.

#define N_RES 512
#define N_IN 8
#define T_STEPS 3000
#define B_SIZE 64
#define NW 12               // waves per block = 256-step body windows
#define THR2 0.5625f        // 0.75^2
#define XSANE 1e3f
#define M2SANE 100.0f

typedef float v2f __attribute__((ext_vector_type(2)));
typedef float v4f __attribute__((ext_vector_type(4)));

__global__ __launch_bounds__(768, 1) void reservoir_fused(
    const float* __restrict__ x,      // [B][8][T]
    const float* __restrict__ W_in,   // [512][8]
    const float* __restrict__ W_rec,  // [512][512]
    float* __restrict__ out)          // [B][512]
{
    __shared__ v4f xs4[2 * (T_STEPS + 1)];   // 96 KB (fallback staging only)
    __shared__ int lflag;

    const int tid = threadIdx.x;
    const int lane = tid & 63;
    const int q = tid >> 6;          // window id 0..11
    const int b = blockIdx.x;

    if (tid == 0) lflag = 0;
    __syncthreads();

    bool bad = false;

    // wmax2 = max_r ||W_r||^2 (8 rows/lane; 16 KB, L2-hot).
    float wmax2 = 0.0f;
#pragma unroll
    for (int n = 0; n < 8; ++n) {
        const int r = lane + (n << 6);
        const float4 wa = *(const float4*)(W_in + r * 8);
        const float4 wb = *(const float4*)(W_in + r * 8 + 4);
        const float s = wa.x*wa.x + wa.y*wa.y + wa.z*wa.z + wa.w*wa.w
                      + wb.x*wb.x + wb.y*wb.y + wb.z*wb.z + wb.w*wb.w;
        wmax2 = fmaxf(wmax2, s);
    }
#pragma unroll
    for (int off = 32; off >= 1; off >>= 1)
        wmax2 = fmaxf(wmax2, __shfl_xor(wmax2, off));
    bad |= !(wmax2 <= M2SANE);       // NaN-safe sanity on weights
    wmax2 *= 1.00001f;

    const float* xb = x + (size_t)b * (N_IN * T_STEPS);
    const int t0 = 256 * (q - 1) + 8 * lane;   // lane's first step
    const bool inr = (t0 >= 0) && (t0 <= T_STEPS - 8);

    float fst[N_IN][8];              // f per (channel, local step) - static idx
    float n2[8];
#pragma unroll
    for (int k = 0; k < 8; ++k) n2[k] = 0.0f;

    const float m1 = (lane >= 1) ? 0.00390625f : 0.0f;        // 0.5^8
    const float m2 = (lane >= 2) ? 1.52587890625e-5f : 0.0f;  // 0.5^16
    const float cm = (lane >= 1) ? 1.0f : 0.0f;

#pragma unroll
    for (int i = 0; i < N_IN; ++i) {
        float xv[8];
        if (inr) {
            const float4 a = *(const float4*)(xb + i * T_STEPS + t0);
            const float4 d = *(const float4*)(xb + i * T_STEPS + t0 + 4);
            xv[0]=a.x; xv[1]=a.y; xv[2]=a.z; xv[3]=a.w;
            xv[4]=d.x; xv[5]=d.y; xv[6]=d.z; xv[7]=d.w;
        } else {
#pragma unroll
            for (int k = 0; k < 8; ++k) xv[k] = 0.0f;
        }
#pragma unroll
        for (int k = 0; k < 8; ++k) bad |= !(fabsf(xv[k]) <= XSANE);

        // Local serial scan from zero: L_k = IIR of this lane's 8 inputs.
        float L[8];
        L[0] = 0.5f * xv[0];
#pragma unroll
        for (int k = 1; k < 8; ++k) L[k] = L[k-1] + (xv[k] - L[k-1]) * 0.5f;

        // Lane-aggregate scan, ratio r = 0.5^8; truncated KS (depth 4 lanes,
        // residual coeff r^4 ~ 2.3e-10 -> negligible vs 0.25 margin).
        float A = L[7];
        A += m1 * __shfl_up(A, 1);
        A += m2 * __shfl_up(A, 2);
        const float c = cm * __shfl_up(A, 1);   // carry = f at lane-1's last step

        const float dk[8] = {0.5f, 0.25f, 0.125f, 0.0625f, 0.03125f,
                             0.015625f, 0.0078125f, 0.00390625f};
#pragma unroll
        for (int k = 0; k < 8; ++k) {
            const float f = fmaf(c, dk[k], L[k]);
            fst[i][k] = f;
            n2[k] = fmaf(f, f, n2[k]);
        }
    }

    // Per-step norm test on body steps (lane >= 32 <=> t >= 256q), with
    // in-wave EXACT 512-dot rescue on failures (v6/v7-validated logic).
#pragma unroll
    for (int k = 0; k < 8; ++k) {
        const bool inb = (lane >= 32) && (t0 + k < T_STEPS);
        const bool fail = inb && !(n2[k] * wmax2 < THR2);   // NaN -> fail
        unsigned long long bal = __ballot(fail);
        while (bal) {
            const int l = (int)__builtin_ctzll(bal);
            bal &= bal - 1;
            float h[8];
#pragma unroll
            for (int i = 0; i < 8; ++i) h[i] = __shfl(fst[i][k], l);
            float vmx = -1e30f;
#pragma unroll
            for (int n = 0; n < 8; ++n) {
                const float* wr = W_in + (lane * 8 + n) * 8;
                float d = 0.f;
#pragma unroll
                for (int i = 0; i < N_IN; ++i) d += wr[i] * h[i];
                vmx = fmaxf(vmx, d);
            }
#pragma unroll
            for (int off = 32; off >= 1; off >>= 1)
                vmx = fmaxf(vmx, __shfl_xor(vmx, off));
            bad |= !(vmx < 0.75f);
        }
    }

    if (__any(bad) && lane == 0) atomicOr(&lflag, 1);
    __syncthreads();

    if (lflag == 0) {
        // Provably spike-free -> spike counts are exactly 0.
        if (tid < N_RES) out[b * N_RES + tid] = 0.0f;
        return;
    }

    // ---- exact serial fallback (validated v2 wave structure) ----
    float* xsf = (float*)xs4;
#pragma unroll
    for (int i = 0; i < N_IN; ++i)
        for (int t = tid; t < T_STEPS; t += 768)
            xsf[t * 8 + i] = xb[i * T_STEPS + t];
    if (tid < 8) xsf[T_STEPS * 8 + tid] = 0.0f;
    __syncthreads();

    if (tid >= 64) return;

    v2f w2[4][N_IN];
#pragma unroll
    for (int p = 0; p < 4; ++p) {
        const int r0 = (2 * p) * 64 + lane;
        const int r1 = r0 + 64;
#pragma unroll
        for (int i = 0; i < N_IN; ++i)
            w2[p][i] = (v2f){ W_in[r0 * N_IN + i], W_in[r1 * N_IN + i] };
    }

    v2f v[4], acc[4];
#pragma unroll
    for (int p = 0; p < 4; ++p) { v[p] = (v2f)0.0f; acc[p] = (v2f)0.0f; }

    unsigned long long mask[8];
#pragma unroll
    for (int k = 0; k < 8; ++k) mask[k] = 0ULL;

    v4f xlo = xs4[0], xhi = xs4[1];

    for (int t = 0; t < T_STEPS; ++t) {
        v4f nlo = xs4[2 * t + 2];
        v4f nhi = xs4[2 * t + 3];

        v2f rec[4];
#pragma unroll
        for (int p = 0; p < 4; ++p) rec[p] = (v2f)0.0f;

        const unsigned long long anym =
            mask[0] | mask[1] | mask[2] | mask[3] |
            mask[4] | mask[5] | mask[6] | mask[7];
        if (anym) {
#pragma unroll
            for (int k2 = 0; k2 < 8; ++k2) {
                unsigned long long m = mask[k2];
                while (m) {
                    const int j = (k2 << 6) + __builtin_ctzll(m);
                    m &= m - 1;
#pragma unroll
                    for (int p = 0; p < 4; ++p) {
                        const int r0 = (2 * p) * 64 + lane;
                        rec[p].x += W_rec[(size_t)r0 * N_RES + j];
                        rec[p].y += W_rec[(size_t)(r0 + 64) * N_RES + j];
                    }
                }
            }
        }

        const float xff[8] = { xlo.x, xlo.y, xlo.z, xlo.w,
                               xhi.x, xhi.y, xhi.z, xhi.w };
        v2f xp[4];
#pragma unroll
        for (int p = 0; p < 4; ++p) xp[p] = (v2f)0.0f;
#pragma unroll
        for (int i = 0; i < N_IN; ++i) {
            const v2f xv2 = (v2f){ xff[i], xff[i] };
#pragma unroll
            for (int p = 0; p < 4; ++p) xp[p] += w2[p][i] * xv2;
        }
#pragma unroll
        for (int p = 0; p < 4; ++p) xp[p] += rec[p];

#pragma unroll
        for (int p = 0; p < 4; ++p) {
            v[p] = v[p] + (xp[p] - v[p]) * 0.5f;
            const bool s0 = (v[p].x - 1.0f) >= 0.0f;
            const bool s1 = (v[p].y - 1.0f) >= 0.0f;
            mask[2 * p]     = __ballot(s0);
            mask[2 * p + 1] = __ballot(s1);
            if (s0) { v[p].x = 0.0f; acc[p].x += 1.0f; }
            if (s1) { v[p].y = 0.0f; acc[p].y += 1.0f; }
        }

        xlo = nlo; xhi = nhi;
    }

#pragma unroll
    for (int p = 0; p < 4; ++p) {
        const int r0 = (2 * p) * 64 + lane;
        out[b * N_RES + r0]      = acc[p].x / (float)T_STEPS;
        out[b * N_RES + r0 + 64] = acc[p].y / (float)T_STEPS;
    }
}

extern "C" void kernel_launch(void* const* d_in, const int* in_sizes, int n_in,
                              void* d_out, int out_size, void* d_ws, size_t ws_size,
                              hipStream_t stream) {
    const float* x     = (const float*)d_in[0];   // 64*8*3000
    const float* W_in  = (const float*)d_in[1];   // 512*8
    const float* W_rec = (const float*)d_in[2];   // 512*512
    float* out = (float*)d_out;                   // 64*512

    reservoir_fused<<<B_SIZE, 768, 0, stream>>>(x, W_in, W_rec, out);
}